// Round 4
// baseline (491.787 us; speedup 1.0000x reference)
//
#include <hip/hip_runtime.h>

typedef float  f4  __attribute__((ext_vector_type(4)));
typedef short  s8v __attribute__((ext_vector_type(8)));   // 8 bf16 (4 VGPRs)
typedef unsigned short u16;
typedef u16 us4 __attribute__((ext_vector_type(4)));

constexpr int En  = 1024;
constexpr int Wn  = 1024;
constexpr int Bn  = 8;
constexpr int Hn  = 16;
constexpr int DHn = 64;

__device__ inline u16 bf16rn(float x) {
    unsigned u = __float_as_uint(x);
    return (u16)((u + 0x7FFFu + ((u >> 16) & 1u)) >> 16);
}
__device__ inline float bf16tof(u16 h) { return __uint_as_float(((unsigned)h) << 16); }

#define GLD_LDS16(gp, lp) __builtin_amdgcn_global_load_lds(                      \
    (const __attribute__((address_space(1))) void*)(gp),                         \
    (__attribute__((address_space(3))) void*)(lp), 16, 0, 0)

// ---------------------------------------------------------------------------
// Elementwise split of the four 1024x1024 weight matrices (one launch, z=4).
// Slot order in Lsp: [L_K, L_Q, L_V, M] x {hi, lo}.
// ---------------------------------------------------------------------------
__global__ void split_plain4(const float* __restrict__ p0,
                             const float* __restrict__ p1,
                             const float* __restrict__ p2,
                             const float* __restrict__ p3,
                             u16* __restrict__ base) {
    const int z = blockIdx.y;
    const float* in = (z == 0) ? p0 : (z == 1) ? p1 : (z == 2) ? p2 : p3;
    u16* hi = base + (size_t)(2 * z) * En * En;
    u16* lo = base + (size_t)(2 * z + 1) * En * En;
    int i = blockIdx.x * blockDim.x + threadIdx.x;
    f4 v = ((const f4*)in)[i];
    us4 h, l;
    #pragma unroll
    for (int k = 0; k < 4; ++k) {
        u16 hh = bf16rn(v[k]);
        h[k] = hh;
        l[k] = bf16rn(v[k] - bf16tof(hh));
    }
    ((us4*)hi)[i] = h;
    ((us4*)lo)[i] = l;
}

// ---------------------------------------------------------------------------
// Transpose + split: in [z][1024][1024] fp32 -> hi/lo [z][1024][1024] bf16.
// ---------------------------------------------------------------------------
__global__ __launch_bounds__(256)
void split_t(const float* __restrict__ in, u16* __restrict__ hi,
             u16* __restrict__ lo) {
    __shared__ float T[32][33];
    const int z = blockIdx.z;
    const size_t zo = (size_t)z * En * Wn;
    const int r0 = blockIdx.y * 32, c0 = blockIdx.x * 32;
    const int t = threadIdx.x;
    const int row = t >> 3, c4 = (t & 7) << 2;

    f4 v = *(const f4*)&in[zo + (size_t)(r0 + row) * Wn + c0 + c4];
    T[row][c4 + 0] = v[0]; T[row][c4 + 1] = v[1];
    T[row][c4 + 2] = v[2]; T[row][c4 + 3] = v[3];
    __syncthreads();

    const int oc = row, r4 = c4;
    us4 h, l;
    #pragma unroll
    for (int i = 0; i < 4; ++i) {
        float x = T[r4 + i][oc];
        u16 hh = bf16rn(x);
        h[i] = hh;
        l[i] = bf16rn(x - bf16tof(hh));
    }
    *(us4*)&hi[zo + (size_t)(c0 + oc) * En + r0 + r4] = h;
    *(us4*)&lo[zo + (size_t)(c0 + oc) * En + r0 + r4] = l;
}

// ---------------------------------------------------------------------------
// MFMA GEMM with bf16 hi/lo split operands (3-term: hh + hl + lh).
// T2 swizzle on LDS tiles (row-pair super-rows, source pre-swizzled, read XOR).
// B-fragments loaded per-j (live set ~120 VGPR) + launch_bounds(256,3):
// 3 blocks/CU (m97's occupancy regime). Per-acc MFMA order unchanged.
// MODE 0: fp32 out [z][e][w] + bias.
// MODE 1: hi/lo bf16 out in attention QK layout [bh][w][64]  (fuses qk_repack).
// MODE 2: bf16 out in attention V layout [bh][d][w]          (fuses f32_to_bf16).
// ---------------------------------------------------------------------------
template<int MODE>
__global__ __launch_bounds__(256, 3)
void gemm_mfma(const u16* __restrict__ Ah,  const u16* __restrict__ Al,
               const u16* __restrict__ Bth, const u16* __restrict__ Btl,
               float* __restrict__ Yf, u16* __restrict__ Yh, u16* __restrict__ Yl,
               const float* __restrict__ bias) {
    __shared__ u16 AsH[4096], AsL[4096], BsH[4096], BsL[4096];

    const int z  = blockIdx.z;
    const size_t zB = (size_t)z * Wn * En;
    const int e0 = blockIdx.y * 128, n0 = blockIdx.x * 128;
    const int t = threadIdx.x, lane = t & 63, wave = t >> 6;
    const int q = lane >> 4, r = lane & 15;
    const int m_off = (wave & 1) * 64, n_off = (wave >> 1) * 64;

    f4 acc[4][4];
    #pragma unroll
    for (int i = 0; i < 4; ++i)
        #pragma unroll
        for (int j = 0; j < 4; ++j) { acc[i][j][0]=0; acc[i][j][1]=0; acc[i][j][2]=0; acc[i][j][3]=0; }

    for (int kb = 0; kb < En; kb += 32) {
        __syncthreads();
        #pragma unroll
        for (int it = 0; it < 2; ++it) {
            const int id = t + 256 * it;
            // swizzled staging: LDS byte id*16 = super-row u, pos id&7
            // holds logical chunk p = (id&7) ^ (u&7)
            const int u = id >> 3;
            const int p = (id & 7) ^ (u & 7);
            const int m = 2 * u + (p >> 2), g = p & 3;
            const size_t colA = (size_t)kb + 8 * g;
            const u16* ga_h = Ah  + (size_t)(e0 + m) * En + colA;
            const u16* ga_l = Al  + (size_t)(e0 + m) * En + colA;
            const u16* gb_h = Bth + zB + (size_t)(n0 + m) * En + colA;
            const u16* gb_l = Btl + zB + (size_t)(n0 + m) * En + colA;
            GLD_LDS16(ga_h, &AsH[id * 8]);
            GLD_LDS16(ga_l, &AsL[id * 8]);
            GLD_LDS16(gb_h, &BsH[id * 8]);
            GLD_LDS16(gb_l, &BsL[id * 8]);
        }
        __syncthreads();

        s8v aH[4], aL[4];
        #pragma unroll
        for (int i = 0; i < 4; ++i) {
            const int Ra = m_off + 16 * i + r;
            const int sa = ((((Ra & 1) << 2) | q) ^ ((Ra >> 1) & 7));
            const int ai = ((Ra >> 1) * 8 + sa) * 8;
            aH[i] = *(const s8v*)&AsH[ai];
            aL[i] = *(const s8v*)&AsL[ai];
        }
        #pragma unroll
        for (int j = 0; j < 4; ++j) {
            const int Rb = n_off + 16 * j + r;
            const int sb = ((((Rb & 1) << 2) | q) ^ ((Rb >> 1) & 7));
            const int bi = ((Rb >> 1) * 8 + sb) * 8;
            s8v bH = *(const s8v*)&BsH[bi];
            s8v bL = *(const s8v*)&BsL[bi];
            #pragma unroll
            for (int i = 0; i < 4; ++i) {
                acc[i][j] = __builtin_amdgcn_mfma_f32_16x16x32_bf16(aH[i], bH, acc[i][j], 0, 0, 0);
                acc[i][j] = __builtin_amdgcn_mfma_f32_16x16x32_bf16(aH[i], bL, acc[i][j], 0, 0, 0);
                acc[i][j] = __builtin_amdgcn_mfma_f32_16x16x32_bf16(aL[i], bH, acc[i][j], 0, 0, 0);
            }
        }
    }

    if constexpr (MODE == 0) {
        const size_t zY = (size_t)z * En * Wn;
        #pragma unroll
        for (int i = 0; i < 4; ++i) {
            #pragma unroll
            for (int reg = 0; reg < 4; ++reg) {
                const int e = e0 + m_off + 16 * i + q * 4 + reg;
                const float bv = bias ? bias[e] : 0.0f;
                #pragma unroll
                for (int j = 0; j < 4; ++j) {
                    const int w = n0 + n_off + 16 * j + r;
                    Yf[zY + (size_t)e * Wn + w] = acc[i][j][reg] + bv;
                }
            }
        }
    }
    if constexpr (MODE == 1) {
        // hi/lo split into [bh][w][64]; 4 regs = 4 consecutive d values
        #pragma unroll
        for (int i = 0; i < 4; ++i) {
            const int e_base = e0 + m_off + 16 * i + q * 4;
            const int bh_e = z * Hn + (e_base >> 6);
            const int d0 = e_base & 63;
            #pragma unroll
            for (int j = 0; j < 4; ++j) {
                const int w = n0 + n_off + 16 * j + r;
                us4 h, l;
                #pragma unroll
                for (int reg = 0; reg < 4; ++reg) {
                    float x = acc[i][j][reg];
                    u16 hh = bf16rn(x);
                    h[reg] = hh;
                    l[reg] = bf16rn(x - bf16tof(hh));
                }
                const size_t o = ((size_t)bh_e * Wn + w) * 64 + d0;
                *(us4*)&Yh[o] = h;
                *(us4*)&Yl[o] = l;
            }
        }
    }
    if constexpr (MODE == 2) {
        // bf16 cast into [bh][d][w]
        #pragma unroll
        for (int i = 0; i < 4; ++i) {
            #pragma unroll
            for (int reg = 0; reg < 4; ++reg) {
                const int e = e0 + m_off + 16 * i + q * 4 + reg;
                const int bh_e = z * Hn + (e >> 6);
                const int d = e & 63;
                const size_t ro = ((size_t)bh_e * 64 + d) * Wn;
                #pragma unroll
                for (int j = 0; j < 4; ++j) {
                    const int w = n0 + n_off + 16 * j + r;
                    Yh[ro + w] = bf16rn(acc[i][j][reg]);
                }
            }
        }
    }
}

// ---------------------------------------------------------------------------
// MFMA flash attention v3: single LDS buffer + T14 register prefetch
// (global->reg issued after the post-write barrier, overlaps full compute;
// ds_write at next iteration top). LDS 33 KB -> 4 blocks/CU (launch_bounds 4).
// T2 swizzle on Qs/Vs (source pre-swizzled chunks, read XOR).
// T5 setprio around MFMA clusters (attn-positive per m191).
// Epilogue writes AoT hi/lo [w][e] directly (fuses split_t of Ao).
// ---------------------------------------------------------------------------
__global__ __launch_bounds__(256, 4)
void attn_mfma3(const u16* __restrict__ QTh, const u16* __restrict__ QTl,
                const u16* __restrict__ KTh, const u16* __restrict__ KTl,
                const u16* __restrict__ Vb,  u16* __restrict__ AoTh,
                u16* __restrict__ AoTl) {
    __shared__ u16 QsH[4096], QsL[4096], Vs[4096];   // [q][d] chunks, swizzled
    __shared__ u16 PT[4][16][72];                    // per-wave P^T

    const int id   = blockIdx.x;
    const int rest = id >> 3;
    const int kb   = 15 - (rest & 15);              // long blocks first
    const int bh   = (id & 7) + 8 * (rest >> 4);    // id%8 fixed per bh -> XCD

    const int t = threadIdx.x, lane = t & 63, wave = t >> 6;
    const int r = lane & 15, quad = lane >> 4;
    const int k0 = kb * 64;
    const int kcol = k0 + wave * 16 + r;
    u16 (*pt)[72] = PT[wave];

    const size_t qkb = (size_t)bh * Wn * 64;        // [w][64]
    const size_t vbb = (size_t)bh * 64 * Wn;        // [d][w]

    // K fragments: once per block, in registers (straight from global).
    s8v kH[2], kL[2];
    #pragma unroll
    for (int s = 0; s < 2; ++s) {
        const size_t a = qkb + (size_t)kcol * 64 + s * 32 + quad * 8;
        kH[s] = *(const s8v*)&KTh[a];
        kL[s] = *(const s8v*)&KTl[a];
    }

    f4 o[4];
    #pragma unroll
    for (int i = 0; i < 4; ++i) { o[i][0]=0; o[i][1]=0; o[i][2]=0; o[i][3]=0; }
    float m = -1e30f, l = 0.0f;

    // per-thread staging chunk addressing (source pre-swizzled, LDS linear)
    const int c0 = t,       row0 = c0 >> 3, p0 = (c0 & 7) ^ (row0 & 7);
    const int c1 = t + 256, row1 = c1 >> 3, p1 = (c1 & 7) ^ (row1 & 7);

    s8v Aqh0, Aqh1, Aql0, Aql1, Av0, Av1;   // reg-staged tile (set A)
    s8v Bqh0, Bqh1, Bql0, Bql1, Bv0, Bv1;   // reg-staged tile (set B)

    auto ld = [&](int q0, s8v& qh0, s8v& qh1, s8v& ql0, s8v& ql1,
                  s8v& v0, s8v& v1) {
        const size_t g = qkb + (size_t)q0 * 64;
        qh0 = *(const s8v*)&QTh[g + (size_t)row0 * 64 + p0 * 8];
        ql0 = *(const s8v*)&QTl[g + (size_t)row0 * 64 + p0 * 8];
        v0  = *(const s8v*)&Vb[vbb + (size_t)row0 * Wn + q0 + p0 * 8];
        qh1 = *(const s8v*)&QTh[g + (size_t)row1 * 64 + p1 * 8];
        ql1 = *(const s8v*)&QTl[g + (size_t)row1 * 64 + p1 * 8];
        v1  = *(const s8v*)&Vb[vbb + (size_t)row1 * Wn + q0 + p1 * 8];
    };
    auto wr = [&](s8v& qh0, s8v& qh1, s8v& ql0, s8v& ql1, s8v& v0, s8v& v1) {
        *(s8v*)&QsH[c0 * 8] = qh0; *(s8v*)&QsL[c0 * 8] = ql0; *(s8v*)&Vs[c0 * 8] = v0;
        *(s8v*)&QsH[c1 * 8] = qh1; *(s8v*)&QsL[c1 * 8] = ql1; *(s8v*)&Vs[c1 * 8] = v1;
    };

    auto compute = [&](int q0) {
        // ---- S = Q^T K (3-term hi/lo split), frags from LDS (swizzled read)
        f4 sacc[4];
        #pragma unroll
        for (int mt = 0; mt < 4; ++mt) { sacc[mt][0]=0; sacc[mt][1]=0; sacc[mt][2]=0; sacc[mt][3]=0; }
        __builtin_amdgcn_s_setprio(1);
        #pragma unroll
        for (int s = 0; s < 2; ++s) {
            const int sw = (((s * 4 + quad) ^ (r & 7)) << 3);
            #pragma unroll
            for (int mt = 0; mt < 4; ++mt) {
                const int a = (16 * mt + r) * 64 + sw;
                s8v qh = *(const s8v*)&QsH[a];
                s8v ql = *(const s8v*)&QsL[a];
                sacc[mt] = __builtin_amdgcn_mfma_f32_16x16x32_bf16(qh, kH[s], sacc[mt], 0, 0, 0);
                sacc[mt] = __builtin_amdgcn_mfma_f32_16x16x32_bf16(qh, kL[s], sacc[mt], 0, 0, 0);
                sacc[mt] = __builtin_amdgcn_mfma_f32_16x16x32_bf16(ql, kH[s], sacc[mt], 0, 0, 0);
            }
        }
        __builtin_amdgcn_s_setprio(0);
        // ---- causal mask on the diagonal tile
        if (q0 == k0) {
            const int klocal = wave * 16 + r;
            #pragma unroll
            for (int mt = 0; mt < 4; ++mt)
                #pragma unroll
                for (int reg = 0; reg < 4; ++reg)
                    if (16 * mt + quad * 4 + reg > klocal) sacc[mt][reg] = -1e30f;
        }
        // ---- online softmax over q (per-lane column), quad reduce via shfl
        float tm = -1e30f;
        #pragma unroll
        for (int mt = 0; mt < 4; ++mt)
            #pragma unroll
            for (int reg = 0; reg < 4; ++reg) tm = fmaxf(tm, sacc[mt][reg]);
        tm = fmaxf(tm, __shfl_xor(tm, 16));
        tm = fmaxf(tm, __shfl_xor(tm, 32));
        const float mnew  = fmaxf(m, tm);
        const float alpha = __expf(m - mnew);
        float ps = 0.0f;
        #pragma unroll
        for (int mt = 0; mt < 4; ++mt) {
            us4 pk;
            #pragma unroll
            for (int reg = 0; reg < 4; ++reg) {
                float p = __expf(sacc[mt][reg] - mnew);
                ps += p;
                pk[reg] = bf16rn(p);
            }
            *(us4*)&pt[r][16 * mt + quad * 4] = pk;
        }
        ps += __shfl_xor(ps, 16);
        ps += __shfl_xor(ps, 32);
        l = l * alpha + ps;
        m = mnew;
        #pragma unroll
        for (int i = 0; i < 4; ++i) {
            o[i][0] *= alpha; o[i][1] *= alpha; o[i][2] *= alpha; o[i][3] *= alpha;
        }
        // ---- O += V P (V frags from LDS swizzled, P^T frags from per-wave LDS)
        __builtin_amdgcn_s_setprio(1);
        #pragma unroll
        for (int s = 0; s < 2; ++s) {
            const int sw = (((s * 4 + quad) ^ (r & 7)) << 3);
            s8v pf = *(const s8v*)&pt[r][s * 32 + quad * 8];
            #pragma unroll
            for (int i = 0; i < 4; ++i) {
                s8v vf = *(const s8v*)&Vs[(16 * i + r) * 64 + sw];
                o[i] = __builtin_amdgcn_mfma_f32_16x16x32_bf16(vf, pf, o[i], 0, 0, 0);
            }
        }
        __builtin_amdgcn_s_setprio(0);
    };

    ld(0, Aqh0, Aqh1, Aql0, Aql1, Av0, Av1);
    int q0 = 0;
    for (;;) {
        __syncthreads();                                // LDS reads of prev iter done
        wr(Aqh0, Aqh1, Aql0, Aql1, Av0, Av1);
        __syncthreads();                                // ds_writes visible
        if (q0 + 64 <= k0) ld(q0 + 64, Bqh0, Bqh1, Bql0, Bql1, Bv0, Bv1);
        compute(q0);
        q0 += 64;
        if (q0 > k0) break;
        __syncthreads();
        wr(Bqh0, Bqh1, Bql0, Bql1, Bv0, Bv1);
        __syncthreads();
        if (q0 + 64 <= k0) ld(q0 + 64, Aqh0, Aqh1, Aql0, Aql1, Av0, Av1);
        compute(q0);
        q0 += 64;
        if (q0 > k0) break;
    }

    // ---- epilogue: hi/lo split straight into AoT [w][e] (per batch)
    const float inv = 1.0f / (l * 32.0f);
    const size_t ob0 = (size_t)(bh >> 4) * ((size_t)Wn * En) +
                       (size_t)kcol * En + (bh & 15) * 64 + quad * 4;
    #pragma unroll
    for (int i = 0; i < 4; ++i) {
        us4 h, lo4;
        #pragma unroll
        for (int reg = 0; reg < 4; ++reg) {
            float x = o[i][reg] * inv;
            u16 hh = bf16rn(x);
            h[reg] = hh;
            lo4[reg] = bf16rn(x - bf16tof(hh));
        }
        *(us4*)&AoTh[ob0 + 16 * i] = h;
        *(us4*)&AoTl[ob0 + 16 * i] = lo4;
    }
}

// ---------------------------------------------------------------------------
// fp32 fallback GEMM + attention (round-2 proven).
// ---------------------------------------------------------------------------
__global__ __launch_bounds__(256, 2)
void gemm128(const float* __restrict__ L, const float* __restrict__ X,
             float* __restrict__ Y, const float* __restrict__ bias) {
    __shared__ float As[16][132];
    __shared__ float Bs[16][132];

    const int bz = blockIdx.z;
    const float* Xb = X + (size_t)bz * En * Wn;
    float*       Yb = Y + (size_t)bz * En * Wn;
    const int e0 = blockIdx.y * 128;
    const int w0 = blockIdx.x * 128;
    const int t  = threadIdx.x;
    const int tx = t & 15, ty = t >> 4;
    const int la_e = t >> 2, la_f = (t & 3) << 2;
    const int lb_f = t >> 5, lb_w = (t & 31) << 2;

    float acc[2][2][4][4] = {};

    for (int f0 = 0; f0 < En; f0 += 16) {
        f4 a0 = *(const f4*)&L [(size_t)(e0 + la_e)      * En + f0 + la_f];
        f4 a1 = *(const f4*)&L [(size_t)(e0 + la_e + 64) * En + f0 + la_f];
        f4 b0 = *(const f4*)&Xb[(size_t)(f0 + lb_f)      * Wn + w0 + lb_w];
        f4 b1 = *(const f4*)&Xb[(size_t)(f0 + lb_f + 8)  * Wn + w0 + lb_w];
        __syncthreads();
        As[la_f + 0][la_e] = a0[0]; As[la_f + 1][la_e] = a0[1];
        As[la_f + 2][la_e] = a0[2]; As[la_f + 3][la_e] = a0[3];
        As[la_f + 0][la_e + 64] = a1[0]; As[la_f + 1][la_e + 64] = a1[1];
        As[la_f + 2][la_e + 64] = a1[2]; As[la_f + 3][la_e + 64] = a1[3];
        *(f4*)&Bs[lb_f    ][lb_w] = b0;
        *(f4*)&Bs[lb_f + 8][lb_w] = b1;
        __syncthreads();
        #pragma unroll
        for (int kk = 0; kk < 16; ++kk) {
            f4 av0 = *(f4*)&As[kk][ty * 4];
            f4 av1 = *(f4*)&As[kk][ty * 4 + 64];
            f4 bv0 = *(f4*)&Bs[kk][tx * 4];
            f4 bv1 = *(f4*)&Bs[kk][tx * 4 + 64];
            #pragma unroll
            for (int i = 0; i < 4; ++i)
                #pragma unroll
                for (int j = 0; j < 4; ++j) {
                    acc[0][0][i][j] = fmaf(av0[i], bv0[j], acc[0][0][i][j]);
                    acc[0][1][i][j] = fmaf(av0[i], bv1[j], acc[0][1][i][j]);
                    acc[1][0][i][j] = fmaf(av1[i], bv0[j], acc[1][0][i][j]);
                    acc[1][1][i][j] = fmaf(av1[i], bv1[j], acc[1][1][i][j]);
                }
        }
    }

    #pragma unroll
    for (int eh = 0; eh < 2; ++eh)
        #pragma unroll
        for (int i = 0; i < 4; ++i) {
            const int e = e0 + eh * 64 + ty * 4 + i;
            const float bv = bias ? bias[e] : 0.0f;
            #pragma unroll
            for (int wh = 0; wh < 2; ++wh) {
                f4 v;
                #pragma unroll
                for (int j = 0; j < 4; ++j) v[j] = acc[eh][wh][i][j] + bv;
                *(f4*)&Yb[(size_t)e * Wn + w0 + wh * 64 + tx * 4] = v;
            }
        }
}

__global__ __launch_bounds__(256, 2)
void attn64(const float* __restrict__ Qg, const float* __restrict__ Kg,
            const float* __restrict__ Vg, float* __restrict__ Og) {
    __shared__ float Ks[64][68];
    __shared__ float QP[64][68];
    __shared__ float Vt[64][68];
    __shared__ float mArr[64], lArr[64], alphaArr[64];
    __shared__ float red[4][64];

    const int kb = blockIdx.x, h = blockIdx.y, b = blockIdx.z;
    const size_t base = ((size_t)b * En + (size_t)h * DHn) * Wn;
    const float* Qp = Qg + base;
    const float* Kp = Kg + base;
    const float* Vp = Vg + base;
    float*       Op = Og + base;

    const int t  = threadIdx.x;
    const int tx = t & 15, ty = t >> 4;
    const int lr = t >> 4;
    const int lc = (t & 15) << 2;
    const int k0 = kb * 64;
    const int kc = t & 63, qg = t >> 6;

    #pragma unroll
    for (int r = 0; r < 4; ++r)
        *(f4*)&Ks[lr + r * 16][lc] =
            *(const f4*)&Kp[(size_t)(lr + r * 16) * Wn + k0 + lc];
    if (t < 64) { mArr[t] = -1e30f; lArr[t] = 0.0f; }
    float acc[4][4] = {};
    __syncthreads();

    for (int q0 = 0; q0 <= k0; q0 += 64) {
        #pragma unroll
        for (int r = 0; r < 4; ++r) {
            const int d = lr + r * 16;
            f4 qv = *(const f4*)&Qp[(size_t)d * Wn + q0 + lc];
            f4 vv = *(const f4*)&Vp[(size_t)d * Wn + q0 + lc];
            *(f4*)&QP[d][lc] = qv;
            Vt[lc + 0][d] = vv[0]; Vt[lc + 1][d] = vv[1];
            Vt[lc + 2][d] = vv[2]; Vt[lc + 3][d] = vv[3];
        }
        __syncthreads();

        float s[4][4] = {};
        #pragma unroll 4
        for (int d = 0; d < 64; ++d) {
            f4 kv = *(f4*)&Ks[d][tx * 4];
            f4 q2 = *(f4*)&QP[d][ty * 4];
            #pragma unroll
            for (int i = 0; i < 4; ++i)
                #pragma unroll
                for (int j = 0; j < 4; ++j)
                    s[i][j] = fmaf(q2[i], kv[j], s[i][j]);
        }
        if (q0 == k0) {
            #pragma unroll
            for (int i = 0; i < 4; ++i)
                #pragma unroll
                for (int j = 0; j < 4; ++j)
                    if (ty * 4 + i > tx * 4 + j) s[i][j] = -1e30f;
        }
        __syncthreads();
        #pragma unroll
        for (int i = 0; i < 4; ++i) {
            f4 v;
            #pragma unroll
            for (int j = 0; j < 4; ++j) v[j] = s[i][j];
            *(f4*)&QP[ty * 4 + i][tx * 4] = v;
        }
        __syncthreads();

        float sv[16];
        float lm = -1e30f;
        #pragma unroll
        for (int r = 0; r < 16; ++r) {
            sv[r] = QP[qg * 16 + r][kc];
            lm = fmaxf(lm, sv[r]);
        }
        red[qg][kc] = lm;
        __syncthreads();
        const float mt    = fmaxf(fmaxf(red[0][kc], red[1][kc]),
                                  fmaxf(red[2][kc], red[3][kc]));
        const float mprev = mArr[kc];
        const float mnew  = fmaxf(mprev, mt);
        float psum = 0.0f;
        #pragma unroll
        for (int r = 0; r < 16; ++r) {
            const float p = __expf(sv[r] - mnew);
            psum += p;
            QP[qg * 16 + r][kc] = p;
        }
        __syncthreads();
        red[qg][kc] = psum;
        __syncthreads();
        if (qg == 0) {
            const float alpha = __expf(mprev - mnew);
            lArr[kc] = lArr[kc] * alpha +
                       (red[0][kc] + red[1][kc] + red[2][kc] + red[3][kc]);
            mArr[kc]     = mnew;
            alphaArr[kc] = alpha;
        }
        __syncthreads();

        f4 al = *(f4*)&alphaArr[tx * 4];
        #pragma unroll
        for (int i = 0; i < 4; ++i)
            #pragma unroll
            for (int j = 0; j < 4; ++j)
                acc[i][j] *= al[j];
        #pragma unroll 4
        for (int q = 0; q < 64; ++q) {
            f4 pv = *(f4*)&QP[q][tx * 4];
            f4 v2 = *(f4*)&Vt[q][ty * 4];
            #pragma unroll
            for (int i = 0; i < 4; ++i)
                #pragma unroll
                for (int j = 0; j < 4; ++j)
                    acc[i][j] = fmaf(v2[i], pv[j], acc[i][j]);
        }
        __syncthreads();
    }

    f4 linv = *(f4*)&lArr[tx * 4];
    #pragma unroll
    for (int j = 0; j < 4; ++j) linv[j] = 1.0f / (linv[j] * 32.0f);
    #pragma unroll
    for (int i = 0; i < 4; ++i) {
        f4 v;
        #pragma unroll
        for (int j = 0; j < 4; ++j) v[j] = acc[i][j] * linv[j];
        *(f4*)&Op[(size_t)(ty * 4 + i) * Wn + k0 + tx * 4] = v;
    }
}

// ---------------------------------------------------------------------------
extern "C" void kernel_launch(void* const* d_in, const int* in_sizes, int n_in,
                              void* d_out, int out_size, void* d_ws, size_t ws_size,
                              hipStream_t stream) {
    const float* x    = (const float*)d_in[0];   // [3,B,E,W]: x[0]=K, x[1]=Q, x[2]=V
    const float* L_Q  = (const float*)d_in[1];
    const float* L_K  = (const float*)d_in[2];
    const float* L_V  = (const float*)d_in[3];
    const float* M    = (const float*)d_in[4];
    const float* bias = (const float*)d_in[5];
    float* out = (float*)d_out;

    const size_t mat   = (size_t)Bn * En * Wn;       // 8M elements
    const size_t matB  = mat * 4;                    // 33,554,432 bytes
    const size_t lmatB = (size_t)En * En * 2;        // 2 MB per bf16 L piece
    // Lsp 16MB + XT 32 + KT 32 + QT 32 + Vb 16 + AoT 32 = 160 MB
    const size_t need  = 8 * lmatB + 4 * matB + matB / 2 + matB;

    if (ws_size >= need) {
        char* w = (char*)d_ws;
        u16*  Lsp = (u16*)w;                         // 16 MB, 8 pieces
        char* XT  = w + 8 * lmatB;                   // 32 MB: x^T hi/lo
        char* R1  = XT + matB;                       // 32 MB: KT hi/lo
        char* R2  = R1 + matB;                       // 32 MB: QT hi/lo
        char* R3  = R2 + matB;                       // 16 MB: Vb bf16
        char* R4  = R3 + matB / 2;                   // 32 MB: AoT hi/lo

        u16* LKh = Lsp + 0 * (lmatB / 2); u16* LKl = Lsp + 1 * (lmatB / 2);
        u16* LQh = Lsp + 2 * (lmatB / 2); u16* LQl = Lsp + 3 * (lmatB / 2);
        u16* LVh = Lsp + 4 * (lmatB / 2); u16* LVl = Lsp + 5 * (lmatB / 2);
        u16* Mh  = Lsp + 6 * (lmatB / 2); u16* Ml  = Lsp + 7 * (lmatB / 2);

        u16* XT_H = (u16*)XT;  u16* XT_L = (u16*)(XT + matB / 2);
        u16* KT_h = (u16*)R1;  u16* KT_l = (u16*)(R1 + matB / 2);
        u16* QT_h = (u16*)R2;  u16* QT_l = (u16*)(R2 + matB / 2);
        u16* Vb   = (u16*)R3;
        u16* AoTh = (u16*)R4;  u16* AoTl = (u16*)(R4 + matB / 2);

        const int n4L = En * En / 4;
        // one launch for all four weight splits (slot order LK,LQ,LV,M)
        hipLaunchKernelGGL(split_plain4, dim3(n4L / 256, 4), dim3(256), 0, stream,
                           L_K, L_Q, L_V, M, Lsp);

        dim3 gt(Wn / 32, En / 32, Bn), bt(256);
        dim3 gg(Wn / 128, En / 128, Bn), bg(256);

        // K = L_K @ x[0] -> KT hi/lo directly (fused repack)
        hipLaunchKernelGGL(split_t, gt, bt, 0, stream, x + 0 * mat, XT_H, XT_L);
        hipLaunchKernelGGL(HIP_KERNEL_NAME(gemm_mfma<1>), gg, bg, 0, stream,
                           LKh, LKl, XT_H, XT_L, (float*)nullptr, KT_h, KT_l, (const float*)nullptr);
        // Q = L_Q @ x[1] -> QT hi/lo directly
        hipLaunchKernelGGL(split_t, gt, bt, 0, stream, x + 1 * mat, XT_H, XT_L);
        hipLaunchKernelGGL(HIP_KERNEL_NAME(gemm_mfma<1>), gg, bg, 0, stream,
                           LQh, LQl, XT_H, XT_L, (float*)nullptr, QT_h, QT_l, (const float*)nullptr);
        // V = L_V @ x[2] -> Vb bf16 [bh][d][w] directly
        hipLaunchKernelGGL(split_t, gt, bt, 0, stream, x + 2 * mat, XT_H, XT_L);
        hipLaunchKernelGGL(HIP_KERNEL_NAME(gemm_mfma<2>), gg, bg, 0, stream,
                           LVh, LVl, XT_H, XT_L, (float*)nullptr, Vb, (u16*)nullptr, (const float*)nullptr);

        // attention -> AoT hi/lo directly (fused split_t)
        hipLaunchKernelGGL(attn_mfma3, dim3(2048), dim3(256), 0, stream,
                           QT_h, QT_l, KT_h, KT_l, Vb, AoTh, AoTl);

        // out = M @ Ao + b
        hipLaunchKernelGGL(HIP_KERNEL_NAME(gemm_mfma<0>), gg, bg, 0, stream,
                           Mh, Ml, AoTh, AoTl, out, (u16*)nullptr, (u16*)nullptr, bias);
    } else {
        // fallback: fp32 path (needs 4*matB = 134 MB)
        float* ws = (float*)d_ws;
        float* Kp = ws;
        float* Qp = ws + mat;
        float* Vp = ws + 2 * mat;
        float* Ao = ws + 3 * mat;

        dim3 gg(Wn / 128, En / 128, Bn), blk(256);
        hipLaunchKernelGGL(gemm128, gg, blk, 0, stream, L_K, x + 0 * mat, Kp, (const float*)nullptr);
        hipLaunchKernelGGL(gemm128, gg, blk, 0, stream, L_Q, x + 1 * mat, Qp, (const float*)nullptr);
        hipLaunchKernelGGL(gemm128, gg, blk, 0, stream, L_V, x + 2 * mat, Vp, (const float*)nullptr);

        dim3 ga(Wn / 64, Hn, Bn);
        hipLaunchKernelGGL(attn64, ga, blk, 0, stream, Qp, Kp, Vp, Ao);

        hipLaunchKernelGGL(gemm128, gg, blk, 0, stream, M, Ao, out, bias);
    }
}

// Round 5
// 463.711 us; speedup vs baseline: 1.0605x; 1.0605x over previous
//
#include <hip/hip_runtime.h>

typedef float  f4  __attribute__((ext_vector_type(4)));
typedef short  s8v __attribute__((ext_vector_type(8)));   // 8 bf16 (4 VGPRs)
typedef unsigned short u16;
typedef u16 us4 __attribute__((ext_vector_type(4)));

constexpr int En  = 1024;
constexpr int Wn  = 1024;
constexpr int Bn  = 8;
constexpr int Hn  = 16;
constexpr int DHn = 64;

__device__ inline u16 bf16rn(float x) {
    unsigned u = __float_as_uint(x);
    return (u16)((u + 0x7FFFu + ((u >> 16) & 1u)) >> 16);
}
__device__ inline float bf16tof(u16 h) { return __uint_as_float(((unsigned)h) << 16); }

#define GLD_LDS16(gp, lp) __builtin_amdgcn_global_load_lds(                      \
    (const __attribute__((address_space(1))) void*)(gp),                         \
    (__attribute__((address_space(3))) void*)(lp), 16, 0, 0)

// ---------------------------------------------------------------------------
// Elementwise split of the four 1024x1024 weight matrices (one launch, z=4).
// Slot order in Lsp: [L_K, L_Q, L_V, M] x {hi, lo}.
// ---------------------------------------------------------------------------
__global__ void split_plain4(const float* __restrict__ p0,
                             const float* __restrict__ p1,
                             const float* __restrict__ p2,
                             const float* __restrict__ p3,
                             u16* __restrict__ base) {
    const int z = blockIdx.y;
    const float* in = (z == 0) ? p0 : (z == 1) ? p1 : (z == 2) ? p2 : p3;
    u16* hi = base + (size_t)(2 * z) * En * En;
    u16* lo = base + (size_t)(2 * z + 1) * En * En;
    int i = blockIdx.x * blockDim.x + threadIdx.x;
    f4 v = ((const f4*)in)[i];
    us4 h, l;
    #pragma unroll
    for (int k = 0; k < 4; ++k) {
        u16 hh = bf16rn(v[k]);
        h[k] = hh;
        l[k] = bf16rn(v[k] - bf16tof(hh));
    }
    ((us4*)hi)[i] = h;
    ((us4*)lo)[i] = l;
}

// ---------------------------------------------------------------------------
// Transpose + split: in [z][1024][1024] fp32 -> hi/lo [z][1024][1024] bf16.
// ---------------------------------------------------------------------------
__global__ __launch_bounds__(256)
void split_t(const float* __restrict__ in, u16* __restrict__ hi,
             u16* __restrict__ lo) {
    __shared__ float T[32][33];
    const int z = blockIdx.z;
    const size_t zo = (size_t)z * En * Wn;
    const int r0 = blockIdx.y * 32, c0 = blockIdx.x * 32;
    const int t = threadIdx.x;
    const int row = t >> 3, c4 = (t & 7) << 2;

    f4 v = *(const f4*)&in[zo + (size_t)(r0 + row) * Wn + c0 + c4];
    T[row][c4 + 0] = v[0]; T[row][c4 + 1] = v[1];
    T[row][c4 + 2] = v[2]; T[row][c4 + 3] = v[3];
    __syncthreads();

    const int oc = row, r4 = c4;
    us4 h, l;
    #pragma unroll
    for (int i = 0; i < 4; ++i) {
        float x = T[r4 + i][oc];
        u16 hh = bf16rn(x);
        h[i] = hh;
        l[i] = bf16rn(x - bf16tof(hh));
    }
    *(us4*)&hi[zo + (size_t)(c0 + oc) * En + r0 + r4] = h;
    *(us4*)&lo[zo + (size_t)(c0 + oc) * En + r0 + r4] = l;
}

// ---------------------------------------------------------------------------
// MFMA GEMM with bf16 hi/lo split operands (3-term: hh + hl + lh).
// T2 swizzle on LDS tiles (row-pair super-rows, source pre-swizzled, read XOR).
// B-fragments loaded per-j; launch_bounds(256,3). Measured neutral vs R1 form.
// MODE 0: fp32 out [z][e][w] + bias.
// MODE 1: hi/lo bf16 out in attention QK layout [bh][w][64]  (fuses qk_repack).
// MODE 2: bf16 out in attention V layout [bh][d][w]          (fuses f32_to_bf16).
// ---------------------------------------------------------------------------
template<int MODE>
__global__ __launch_bounds__(256, 3)
void gemm_mfma(const u16* __restrict__ Ah,  const u16* __restrict__ Al,
               const u16* __restrict__ Bth, const u16* __restrict__ Btl,
               float* __restrict__ Yf, u16* __restrict__ Yh, u16* __restrict__ Yl,
               const float* __restrict__ bias) {
    __shared__ u16 AsH[4096], AsL[4096], BsH[4096], BsL[4096];

    const int z  = blockIdx.z;
    const size_t zB = (size_t)z * Wn * En;
    const int e0 = blockIdx.y * 128, n0 = blockIdx.x * 128;
    const int t = threadIdx.x, lane = t & 63, wave = t >> 6;
    const int q = lane >> 4, r = lane & 15;
    const int m_off = (wave & 1) * 64, n_off = (wave >> 1) * 64;

    f4 acc[4][4];
    #pragma unroll
    for (int i = 0; i < 4; ++i)
        #pragma unroll
        for (int j = 0; j < 4; ++j) { acc[i][j][0]=0; acc[i][j][1]=0; acc[i][j][2]=0; acc[i][j][3]=0; }

    for (int kb = 0; kb < En; kb += 32) {
        __syncthreads();
        #pragma unroll
        for (int it = 0; it < 2; ++it) {
            const int id = t + 256 * it;
            // swizzled staging: LDS byte id*16 = super-row u, pos id&7
            // holds logical chunk p = (id&7) ^ (u&7)
            const int u = id >> 3;
            const int p = (id & 7) ^ (u & 7);
            const int m = 2 * u + (p >> 2), g = p & 3;
            const size_t colA = (size_t)kb + 8 * g;
            const u16* ga_h = Ah  + (size_t)(e0 + m) * En + colA;
            const u16* ga_l = Al  + (size_t)(e0 + m) * En + colA;
            const u16* gb_h = Bth + zB + (size_t)(n0 + m) * En + colA;
            const u16* gb_l = Btl + zB + (size_t)(n0 + m) * En + colA;
            GLD_LDS16(ga_h, &AsH[id * 8]);
            GLD_LDS16(ga_l, &AsL[id * 8]);
            GLD_LDS16(gb_h, &BsH[id * 8]);
            GLD_LDS16(gb_l, &BsL[id * 8]);
        }
        __syncthreads();

        s8v aH[4], aL[4];
        #pragma unroll
        for (int i = 0; i < 4; ++i) {
            const int Ra = m_off + 16 * i + r;
            const int sa = ((((Ra & 1) << 2) | q) ^ ((Ra >> 1) & 7));
            const int ai = ((Ra >> 1) * 8 + sa) * 8;
            aH[i] = *(const s8v*)&AsH[ai];
            aL[i] = *(const s8v*)&AsL[ai];
        }
        #pragma unroll
        for (int j = 0; j < 4; ++j) {
            const int Rb = n_off + 16 * j + r;
            const int sb = ((((Rb & 1) << 2) | q) ^ ((Rb >> 1) & 7));
            const int bi = ((Rb >> 1) * 8 + sb) * 8;
            s8v bH = *(const s8v*)&BsH[bi];
            s8v bL = *(const s8v*)&BsL[bi];
            #pragma unroll
            for (int i = 0; i < 4; ++i) {
                acc[i][j] = __builtin_amdgcn_mfma_f32_16x16x32_bf16(aH[i], bH, acc[i][j], 0, 0, 0);
                acc[i][j] = __builtin_amdgcn_mfma_f32_16x16x32_bf16(aH[i], bL, acc[i][j], 0, 0, 0);
                acc[i][j] = __builtin_amdgcn_mfma_f32_16x16x32_bf16(aL[i], bH, acc[i][j], 0, 0, 0);
            }
        }
    }

    if constexpr (MODE == 0) {
        const size_t zY = (size_t)z * En * Wn;
        #pragma unroll
        for (int i = 0; i < 4; ++i) {
            #pragma unroll
            for (int reg = 0; reg < 4; ++reg) {
                const int e = e0 + m_off + 16 * i + q * 4 + reg;
                const float bv = bias ? bias[e] : 0.0f;
                #pragma unroll
                for (int j = 0; j < 4; ++j) {
                    const int w = n0 + n_off + 16 * j + r;
                    Yf[zY + (size_t)e * Wn + w] = acc[i][j][reg] + bv;
                }
            }
        }
    }
    if constexpr (MODE == 1) {
        // hi/lo split into [bh][w][64]; 4 regs = 4 consecutive d values
        #pragma unroll
        for (int i = 0; i < 4; ++i) {
            const int e_base = e0 + m_off + 16 * i + q * 4;
            const int bh_e = z * Hn + (e_base >> 6);
            const int d0 = e_base & 63;
            #pragma unroll
            for (int j = 0; j < 4; ++j) {
                const int w = n0 + n_off + 16 * j + r;
                us4 h, l;
                #pragma unroll
                for (int reg = 0; reg < 4; ++reg) {
                    float x = acc[i][j][reg];
                    u16 hh = bf16rn(x);
                    h[reg] = hh;
                    l[reg] = bf16rn(x - bf16tof(hh));
                }
                const size_t o = ((size_t)bh_e * Wn + w) * 64 + d0;
                *(us4*)&Yh[o] = h;
                *(us4*)&Yl[o] = l;
            }
        }
    }
    if constexpr (MODE == 2) {
        // bf16 cast into [bh][d][w]
        #pragma unroll
        for (int i = 0; i < 4; ++i) {
            #pragma unroll
            for (int reg = 0; reg < 4; ++reg) {
                const int e = e0 + m_off + 16 * i + q * 4 + reg;
                const int bh_e = z * Hn + (e >> 6);
                const int d = e & 63;
                const size_t ro = ((size_t)bh_e * 64 + d) * Wn;
                #pragma unroll
                for (int j = 0; j < 4; ++j) {
                    const int w = n0 + n_off + 16 * j + r;
                    Yh[ro + w] = bf16rn(acc[i][j][reg]);
                }
            }
        }
    }
}

// ---------------------------------------------------------------------------
// MFMA flash attention v3 (R1-proven config): single LDS buffer + T14 register
// prefetch; LDS 33 KB; __launch_bounds__(256,3) -- (256,4) caused VGPR spills
// (VGPR 76->64, WRITE_SIZE 3.4x from scratch traffic, +23 us). No setprio
// (lockstep 4-wave barriers = m190 null case).
// NEW: T13 defer-max (THR=8): skip alpha/l/O rescale when the tile max stays
// within 8 of the running max (wave-uniform). Math exact; P bounded by e^8.
// Epilogue writes AoT hi/lo [w][e] directly (fuses split_t of Ao).
// ---------------------------------------------------------------------------
__global__ __launch_bounds__(256, 3)
void attn_mfma3(const u16* __restrict__ QTh, const u16* __restrict__ QTl,
                const u16* __restrict__ KTh, const u16* __restrict__ KTl,
                const u16* __restrict__ Vb,  u16* __restrict__ AoTh,
                u16* __restrict__ AoTl) {
    __shared__ u16 QsH[4096], QsL[4096], Vs[4096];   // [q][d] chunks, swizzled
    __shared__ u16 PT[4][16][72];                    // per-wave P^T

    const int id   = blockIdx.x;
    const int rest = id >> 3;
    const int kb   = 15 - (rest & 15);              // long blocks first
    const int bh   = (id & 7) + 8 * (rest >> 4);    // id%8 fixed per bh -> XCD

    const int t = threadIdx.x, lane = t & 63, wave = t >> 6;
    const int r = lane & 15, quad = lane >> 4;
    const int k0 = kb * 64;
    const int kcol = k0 + wave * 16 + r;
    u16 (*pt)[72] = PT[wave];

    const size_t qkb = (size_t)bh * Wn * 64;        // [w][64]
    const size_t vbb = (size_t)bh * 64 * Wn;        // [d][w]

    // K fragments: once per block, in registers (straight from global).
    s8v kH[2], kL[2];
    #pragma unroll
    for (int s = 0; s < 2; ++s) {
        const size_t a = qkb + (size_t)kcol * 64 + s * 32 + quad * 8;
        kH[s] = *(const s8v*)&KTh[a];
        kL[s] = *(const s8v*)&KTl[a];
    }

    f4 o[4];
    #pragma unroll
    for (int i = 0; i < 4; ++i) { o[i][0]=0; o[i][1]=0; o[i][2]=0; o[i][3]=0; }
    float m = -1e30f, l = 0.0f;

    // per-thread staging chunk addressing (source pre-swizzled, LDS linear)
    const int c0 = t,       row0 = c0 >> 3, p0 = (c0 & 7) ^ (row0 & 7);
    const int c1 = t + 256, row1 = c1 >> 3, p1 = (c1 & 7) ^ (row1 & 7);

    s8v Aqh0, Aqh1, Aql0, Aql1, Av0, Av1;   // reg-staged tile (set A)
    s8v Bqh0, Bqh1, Bql0, Bql1, Bv0, Bv1;   // reg-staged tile (set B)

    auto ld = [&](int q0, s8v& qh0, s8v& qh1, s8v& ql0, s8v& ql1,
                  s8v& v0, s8v& v1) {
        const size_t g = qkb + (size_t)q0 * 64;
        qh0 = *(const s8v*)&QTh[g + (size_t)row0 * 64 + p0 * 8];
        ql0 = *(const s8v*)&QTl[g + (size_t)row0 * 64 + p0 * 8];
        v0  = *(const s8v*)&Vb[vbb + (size_t)row0 * Wn + q0 + p0 * 8];
        qh1 = *(const s8v*)&QTh[g + (size_t)row1 * 64 + p1 * 8];
        ql1 = *(const s8v*)&QTl[g + (size_t)row1 * 64 + p1 * 8];
        v1  = *(const s8v*)&Vb[vbb + (size_t)row1 * Wn + q0 + p1 * 8];
    };
    auto wr = [&](s8v& qh0, s8v& qh1, s8v& ql0, s8v& ql1, s8v& v0, s8v& v1) {
        *(s8v*)&QsH[c0 * 8] = qh0; *(s8v*)&QsL[c0 * 8] = ql0; *(s8v*)&Vs[c0 * 8] = v0;
        *(s8v*)&QsH[c1 * 8] = qh1; *(s8v*)&QsL[c1 * 8] = ql1; *(s8v*)&Vs[c1 * 8] = v1;
    };

    auto compute = [&](int q0) {
        // ---- S = Q^T K (3-term hi/lo split), frags from LDS (swizzled read)
        f4 sacc[4];
        #pragma unroll
        for (int mt = 0; mt < 4; ++mt) { sacc[mt][0]=0; sacc[mt][1]=0; sacc[mt][2]=0; sacc[mt][3]=0; }
        #pragma unroll
        for (int s = 0; s < 2; ++s) {
            const int sw = (((s * 4 + quad) ^ (r & 7)) << 3);
            #pragma unroll
            for (int mt = 0; mt < 4; ++mt) {
                const int a = (16 * mt + r) * 64 + sw;
                s8v qh = *(const s8v*)&QsH[a];
                s8v ql = *(const s8v*)&QsL[a];
                sacc[mt] = __builtin_amdgcn_mfma_f32_16x16x32_bf16(qh, kH[s], sacc[mt], 0, 0, 0);
                sacc[mt] = __builtin_amdgcn_mfma_f32_16x16x32_bf16(qh, kL[s], sacc[mt], 0, 0, 0);
                sacc[mt] = __builtin_amdgcn_mfma_f32_16x16x32_bf16(ql, kH[s], sacc[mt], 0, 0, 0);
            }
        }
        // ---- causal mask on the diagonal tile
        if (q0 == k0) {
            const int klocal = wave * 16 + r;
            #pragma unroll
            for (int mt = 0; mt < 4; ++mt)
                #pragma unroll
                for (int reg = 0; reg < 4; ++reg)
                    if (16 * mt + quad * 4 + reg > klocal) sacc[mt][reg] = -1e30f;
        }
        // ---- online softmax over q (per-lane column), quad reduce via shfl
        float tm = -1e30f;
        #pragma unroll
        for (int mt = 0; mt < 4; ++mt)
            #pragma unroll
            for (int reg = 0; reg < 4; ++reg) tm = fmaxf(tm, sacc[mt][reg]);
        tm = fmaxf(tm, __shfl_xor(tm, 16));
        tm = fmaxf(tm, __shfl_xor(tm, 32));
        // T13 defer-max: only rescale when the running max grows by > 8.
        if (!__all(tm - m <= 8.0f)) {
            const float mnew  = fmaxf(m, tm);
            const float alpha = __expf(m - mnew);
            l *= alpha;
            #pragma unroll
            for (int i = 0; i < 4; ++i) {
                o[i][0] *= alpha; o[i][1] *= alpha;
                o[i][2] *= alpha; o[i][3] *= alpha;
            }
            m = mnew;
        }
        float ps = 0.0f;
        #pragma unroll
        for (int mt = 0; mt < 4; ++mt) {
            us4 pk;
            #pragma unroll
            for (int reg = 0; reg < 4; ++reg) {
                float p = __expf(sacc[mt][reg] - m);
                ps += p;
                pk[reg] = bf16rn(p);
            }
            *(us4*)&pt[r][16 * mt + quad * 4] = pk;
        }
        ps += __shfl_xor(ps, 16);
        ps += __shfl_xor(ps, 32);
        l += ps;
        // ---- O += V P (V frags from LDS swizzled, P^T frags from per-wave LDS)
        #pragma unroll
        for (int s = 0; s < 2; ++s) {
            const int sw = (((s * 4 + quad) ^ (r & 7)) << 3);
            s8v pf = *(const s8v*)&pt[r][s * 32 + quad * 8];
            #pragma unroll
            for (int i = 0; i < 4; ++i) {
                s8v vf = *(const s8v*)&Vs[(16 * i + r) * 64 + sw];
                o[i] = __builtin_amdgcn_mfma_f32_16x16x32_bf16(vf, pf, o[i], 0, 0, 0);
            }
        }
    };

    ld(0, Aqh0, Aqh1, Aql0, Aql1, Av0, Av1);
    int q0 = 0;
    for (;;) {
        __syncthreads();                                // LDS reads of prev iter done
        wr(Aqh0, Aqh1, Aql0, Aql1, Av0, Av1);
        __syncthreads();                                // ds_writes visible
        if (q0 + 64 <= k0) ld(q0 + 64, Bqh0, Bqh1, Bql0, Bql1, Bv0, Bv1);
        compute(q0);
        q0 += 64;
        if (q0 > k0) break;
        __syncthreads();
        wr(Bqh0, Bqh1, Bql0, Bql1, Bv0, Bv1);
        __syncthreads();
        if (q0 + 64 <= k0) ld(q0 + 64, Aqh0, Aqh1, Aql0, Aql1, Av0, Av1);
        compute(q0);
        q0 += 64;
        if (q0 > k0) break;
    }

    // ---- epilogue: hi/lo split straight into AoT [w][e] (per batch)
    const float inv = 1.0f / (l * 32.0f);
    const size_t ob0 = (size_t)(bh >> 4) * ((size_t)Wn * En) +
                       (size_t)kcol * En + (bh & 15) * 64 + quad * 4;
    #pragma unroll
    for (int i = 0; i < 4; ++i) {
        us4 h, lo4;
        #pragma unroll
        for (int reg = 0; reg < 4; ++reg) {
            float x = o[i][reg] * inv;
            u16 hh = bf16rn(x);
            h[reg] = hh;
            lo4[reg] = bf16rn(x - bf16tof(hh));
        }
        *(us4*)&AoTh[ob0 + 16 * i] = h;
        *(us4*)&AoTl[ob0 + 16 * i] = lo4;
    }
}

// ---------------------------------------------------------------------------
// fp32 fallback GEMM + attention (round-2 proven).
// ---------------------------------------------------------------------------
__global__ __launch_bounds__(256, 2)
void gemm128(const float* __restrict__ L, const float* __restrict__ X,
             float* __restrict__ Y, const float* __restrict__ bias) {
    __shared__ float As[16][132];
    __shared__ float Bs[16][132];

    const int bz = blockIdx.z;
    const float* Xb = X + (size_t)bz * En * Wn;
    float*       Yb = Y + (size_t)bz * En * Wn;
    const int e0 = blockIdx.y * 128;
    const int w0 = blockIdx.x * 128;
    const int t  = threadIdx.x;
    const int tx = t & 15, ty = t >> 4;
    const int la_e = t >> 2, la_f = (t & 3) << 2;
    const int lb_f = t >> 5, lb_w = (t & 31) << 2;

    float acc[2][2][4][4] = {};

    for (int f0 = 0; f0 < En; f0 += 16) {
        f4 a0 = *(const f4*)&L [(size_t)(e0 + la_e)      * En + f0 + la_f];
        f4 a1 = *(const f4*)&L [(size_t)(e0 + la_e + 64) * En + f0 + la_f];
        f4 b0 = *(const f4*)&Xb[(size_t)(f0 + lb_f)      * Wn + w0 + lb_w];
        f4 b1 = *(const f4*)&Xb[(size_t)(f0 + lb_f + 8)  * Wn + w0 + lb_w];
        __syncthreads();
        As[la_f + 0][la_e] = a0[0]; As[la_f + 1][la_e] = a0[1];
        As[la_f + 2][la_e] = a0[2]; As[la_f + 3][la_e] = a0[3];
        As[la_f + 0][la_e + 64] = a1[0]; As[la_f + 1][la_e + 64] = a1[1];
        As[la_f + 2][la_e + 64] = a1[2]; As[la_f + 3][la_e + 64] = a1[3];
        *(f4*)&Bs[lb_f    ][lb_w] = b0;
        *(f4*)&Bs[lb_f + 8][lb_w] = b1;
        __syncthreads();
        #pragma unroll
        for (int kk = 0; kk < 16; ++kk) {
            f4 av0 = *(f4*)&As[kk][ty * 4];
            f4 av1 = *(f4*)&As[kk][ty * 4 + 64];
            f4 bv0 = *(f4*)&Bs[kk][tx * 4];
            f4 bv1 = *(f4*)&Bs[kk][tx * 4 + 64];
            #pragma unroll
            for (int i = 0; i < 4; ++i)
                #pragma unroll
                for (int j = 0; j < 4; ++j) {
                    acc[0][0][i][j] = fmaf(av0[i], bv0[j], acc[0][0][i][j]);
                    acc[0][1][i][j] = fmaf(av0[i], bv1[j], acc[0][1][i][j]);
                    acc[1][0][i][j] = fmaf(av1[i], bv0[j], acc[1][0][i][j]);
                    acc[1][1][i][j] = fmaf(av1[i], bv1[j], acc[1][1][i][j]);
                }
        }
    }

    #pragma unroll
    for (int eh = 0; eh < 2; ++eh)
        #pragma unroll
        for (int i = 0; i < 4; ++i) {
            const int e = e0 + eh * 64 + ty * 4 + i;
            const float bv = bias ? bias[e] : 0.0f;
            #pragma unroll
            for (int wh = 0; wh < 2; ++wh) {
                f4 v;
                #pragma unroll
                for (int j = 0; j < 4; ++j) v[j] = acc[eh][wh][i][j] + bv;
                *(f4*)&Yb[(size_t)e * Wn + w0 + wh * 64 + tx * 4] = v;
            }
        }
}

__global__ __launch_bounds__(256, 2)
void attn64(const float* __restrict__ Qg, const float* __restrict__ Kg,
            const float* __restrict__ Vg, float* __restrict__ Og) {
    __shared__ float Ks[64][68];
    __shared__ float QP[64][68];
    __shared__ float Vt[64][68];
    __shared__ float mArr[64], lArr[64], alphaArr[64];
    __shared__ float red[4][64];

    const int kb = blockIdx.x, h = blockIdx.y, b = blockIdx.z;
    const size_t base = ((size_t)b * En + (size_t)h * DHn) * Wn;
    const float* Qp = Qg + base;
    const float* Kp = Kg + base;
    const float* Vp = Vg + base;
    float*       Op = Og + base;

    const int t  = threadIdx.x;
    const int tx = t & 15, ty = t >> 4;
    const int lr = t >> 4;
    const int lc = (t & 15) << 2;
    const int k0 = kb * 64;
    const int kc = t & 63, qg = t >> 6;

    #pragma unroll
    for (int r = 0; r < 4; ++r)
        *(f4*)&Ks[lr + r * 16][lc] =
            *(const f4*)&Kp[(size_t)(lr + r * 16) * Wn + k0 + lc];
    if (t < 64) { mArr[t] = -1e30f; lArr[t] = 0.0f; }
    float acc[4][4] = {};
    __syncthreads();

    for (int q0 = 0; q0 <= k0; q0 += 64) {
        #pragma unroll
        for (int r = 0; r < 4; ++r) {
            const int d = lr + r * 16;
            f4 qv = *(const f4*)&Qp[(size_t)d * Wn + q0 + lc];
            f4 vv = *(const f4*)&Vp[(size_t)d * Wn + q0 + lc];
            *(f4*)&QP[d][lc] = qv;
            Vt[lc + 0][d] = vv[0]; Vt[lc + 1][d] = vv[1];
            Vt[lc + 2][d] = vv[2]; Vt[lc + 3][d] = vv[3];
        }
        __syncthreads();

        float s[4][4] = {};
        #pragma unroll 4
        for (int d = 0; d < 64; ++d) {
            f4 kv = *(f4*)&Ks[d][tx * 4];
            f4 q2 = *(f4*)&QP[d][ty * 4];
            #pragma unroll
            for (int i = 0; i < 4; ++i)
                #pragma unroll
                for (int j = 0; j < 4; ++j)
                    s[i][j] = fmaf(q2[i], kv[j], s[i][j]);
        }
        if (q0 == k0) {
            #pragma unroll
            for (int i = 0; i < 4; ++i)
                #pragma unroll
                for (int j = 0; j < 4; ++j)
                    if (ty * 4 + i > tx * 4 + j) s[i][j] = -1e30f;
        }
        __syncthreads();
        #pragma unroll
        for (int i = 0; i < 4; ++i) {
            f4 v;
            #pragma unroll
            for (int j = 0; j < 4; ++j) v[j] = s[i][j];
            *(f4*)&QP[ty * 4 + i][tx * 4] = v;
        }
        __syncthreads();

        float sv[16];
        float lm = -1e30f;
        #pragma unroll
        for (int r = 0; r < 16; ++r) {
            sv[r] = QP[qg * 16 + r][kc];
            lm = fmaxf(lm, sv[r]);
        }
        red[qg][kc] = lm;
        __syncthreads();
        const float mt    = fmaxf(fmaxf(red[0][kc], red[1][kc]),
                                  fmaxf(red[2][kc], red[3][kc]));
        const float mprev = mArr[kc];
        const float mnew  = fmaxf(mprev, mt);
        float psum = 0.0f;
        #pragma unroll
        for (int r = 0; r < 16; ++r) {
            const float p = __expf(sv[r] - mnew);
            psum += p;
            QP[qg * 16 + r][kc] = p;
        }
        __syncthreads();
        red[qg][kc] = psum;
        __syncthreads();
        if (qg == 0) {
            const float alpha = __expf(mprev - mnew);
            lArr[kc] = lArr[kc] * alpha +
                       (red[0][kc] + red[1][kc] + red[2][kc] + red[3][kc]);
            mArr[kc]     = mnew;
            alphaArr[kc] = alpha;
        }
        __syncthreads();

        f4 al = *(f4*)&alphaArr[tx * 4];
        #pragma unroll
        for (int i = 0; i < 4; ++i)
            #pragma unroll
            for (int j = 0; j < 4; ++j)
                acc[i][j] *= al[j];
        #pragma unroll 4
        for (int q = 0; q < 64; ++q) {
            f4 pv = *(f4*)&QP[q][tx * 4];
            f4 v2 = *(f4*)&Vt[q][ty * 4];
            #pragma unroll
            for (int i = 0; i < 4; ++i)
                #pragma unroll
                for (int j = 0; j < 4; ++j)
                    acc[i][j] = fmaf(v2[i], pv[j], acc[i][j]);
        }
        __syncthreads();
    }

    f4 linv = *(f4*)&lArr[tx * 4];
    #pragma unroll
    for (int j = 0; j < 4; ++j) linv[j] = 1.0f / (linv[j] * 32.0f);
    #pragma unroll
    for (int i = 0; i < 4; ++i) {
        f4 v;
        #pragma unroll
        for (int j = 0; j < 4; ++j) v[j] = acc[i][j] * linv[j];
        *(f4*)&Op[(size_t)(ty * 4 + i) * Wn + k0 + tx * 4] = v;
    }
}

// ---------------------------------------------------------------------------
extern "C" void kernel_launch(void* const* d_in, const int* in_sizes, int n_in,
                              void* d_out, int out_size, void* d_ws, size_t ws_size,
                              hipStream_t stream) {
    const float* x    = (const float*)d_in[0];   // [3,B,E,W]: x[0]=K, x[1]=Q, x[2]=V
    const float* L_Q  = (const float*)d_in[1];
    const float* L_K  = (const float*)d_in[2];
    const float* L_V  = (const float*)d_in[3];
    const float* M    = (const float*)d_in[4];
    const float* bias = (const float*)d_in[5];
    float* out = (float*)d_out;

    const size_t mat   = (size_t)Bn * En * Wn;       // 8M elements
    const size_t matB  = mat * 4;                    // 33,554,432 bytes
    const size_t lmatB = (size_t)En * En * 2;        // 2 MB per bf16 L piece
    // Lsp 16MB + XT 32 + KT 32 + QT 32 + Vb 16 + AoT 32 = 160 MB
    const size_t need  = 8 * lmatB + 4 * matB + matB / 2 + matB;

    if (ws_size >= need) {
        char* w = (char*)d_ws;
        u16*  Lsp = (u16*)w;                         // 16 MB, 8 pieces
        char* XT  = w + 8 * lmatB;                   // 32 MB: x^T hi/lo
        char* R1  = XT + matB;                       // 32 MB: KT hi/lo
        char* R2  = R1 + matB;                       // 32 MB: QT hi/lo
        char* R3  = R2 + matB;                       // 16 MB: Vb bf16
        char* R4  = R3 + matB / 2;                   // 32 MB: AoT hi/lo

        u16* LKh = Lsp + 0 * (lmatB / 2); u16* LKl = Lsp + 1 * (lmatB / 2);
        u16* LQh = Lsp + 2 * (lmatB / 2); u16* LQl = Lsp + 3 * (lmatB / 2);
        u16* LVh = Lsp + 4 * (lmatB / 2); u16* LVl = Lsp + 5 * (lmatB / 2);
        u16* Mh  = Lsp + 6 * (lmatB / 2); u16* Ml  = Lsp + 7 * (lmatB / 2);

        u16* XT_H = (u16*)XT;  u16* XT_L = (u16*)(XT + matB / 2);
        u16* KT_h = (u16*)R1;  u16* KT_l = (u16*)(R1 + matB / 2);
        u16* QT_h = (u16*)R2;  u16* QT_l = (u16*)(R2 + matB / 2);
        u16* Vb   = (u16*)R3;
        u16* AoTh = (u16*)R4;  u16* AoTl = (u16*)(R4 + matB / 2);

        const int n4L = En * En / 4;
        // one launch for all four weight splits (slot order LK,LQ,LV,M)
        hipLaunchKernelGGL(split_plain4, dim3(n4L / 256, 4), dim3(256), 0, stream,
                           L_K, L_Q, L_V, M, Lsp);

        dim3 gt(Wn / 32, En / 32, Bn), bt(256);
        dim3 gg(Wn / 128, En / 128, Bn), bg(256);

        // K = L_K @ x[0] -> KT hi/lo directly (fused repack)
        hipLaunchKernelGGL(split_t, gt, bt, 0, stream, x + 0 * mat, XT_H, XT_L);
        hipLaunchKernelGGL(HIP_KERNEL_NAME(gemm_mfma<1>), gg, bg, 0, stream,
                           LKh, LKl, XT_H, XT_L, (float*)nullptr, KT_h, KT_l, (const float*)nullptr);
        // Q = L_Q @ x[1] -> QT hi/lo directly
        hipLaunchKernelGGL(split_t, gt, bt, 0, stream, x + 1 * mat, XT_H, XT_L);
        hipLaunchKernelGGL(HIP_KERNEL_NAME(gemm_mfma<1>), gg, bg, 0, stream,
                           LQh, LQl, XT_H, XT_L, (float*)nullptr, QT_h, QT_l, (const float*)nullptr);
        // V = L_V @ x[2] -> Vb bf16 [bh][d][w] directly
        hipLaunchKernelGGL(split_t, gt, bt, 0, stream, x + 2 * mat, XT_H, XT_L);
        hipLaunchKernelGGL(HIP_KERNEL_NAME(gemm_mfma<2>), gg, bg, 0, stream,
                           LVh, LVl, XT_H, XT_L, (float*)nullptr, Vb, (u16*)nullptr, (const float*)nullptr);

        // attention -> AoT hi/lo directly (fused split_t)
        hipLaunchKernelGGL(attn_mfma3, dim3(2048), dim3(256), 0, stream,
                           QT_h, QT_l, KT_h, KT_l, Vb, AoTh, AoTl);

        // out = M @ Ao + b
        hipLaunchKernelGGL(HIP_KERNEL_NAME(gemm_mfma<0>), gg, bg, 0, stream,
                           Mh, Ml, AoTh, AoTl, out, (u16*)nullptr, (u16*)nullptr, bias);
    } else {
        // fallback: fp32 path (needs 4*matB = 134 MB)
        float* ws = (float*)d_ws;
        float* Kp = ws;
        float* Qp = ws + mat;
        float* Vp = ws + 2 * mat;
        float* Ao = ws + 3 * mat;

        dim3 gg(Wn / 128, En / 128, Bn), blk(256);
        hipLaunchKernelGGL(gemm128, gg, blk, 0, stream, L_K, x + 0 * mat, Kp, (const float*)nullptr);
        hipLaunchKernelGGL(gemm128, gg, blk, 0, stream, L_Q, x + 1 * mat, Qp, (const float*)nullptr);
        hipLaunchKernelGGL(gemm128, gg, blk, 0, stream, L_V, x + 2 * mat, Vp, (const float*)nullptr);

        dim3 ga(Wn / 64, Hn, Bn);
        hipLaunchKernelGGL(attn64, ga, blk, 0, stream, Qp, Kp, Vp, Ao);

        hipLaunchKernelGGL(gemm128, gg, blk, 0, stream, M, Ao, out, bias);
    }
}